// Round 4
// baseline (554.787 us; speedup 1.0000x reference)
//
#include <hip/hip_runtime.h>
#include <hip/hip_bf16.h>
#include <stdint.h>

#define Bsz 512
#define Ssz 64
#define Esz 768
#define Dsz 256
#define MROWS (Bsz * Ssz)   // 32768
#define FIN 1024

typedef _Float16 f16;
typedef f16 f16x8v __attribute__((ext_vector_type(8)));
typedef short short8 __attribute__((ext_vector_type(8)));
typedef float f32x4 __attribute__((ext_vector_type(4)));

// round-to-nearest-even f32 -> bf16 bits
__device__ __forceinline__ uint32_t f2bf(float f) {
    uint32_t u = __float_as_uint(f);
    u += 0x7fffu + ((u >> 16) & 1u);
    return u >> 16;
}

// ---------------------------------------------------------------------------
// prep: Wp (3x[256][768] f32) -> f16; corr -> corrT f16 [e][d]; Wb -> bf16
__global__ __launch_bounds__(256) void prep(const float* __restrict__ Wp0,
                                            const float* __restrict__ Wp1,
                                            const float* __restrict__ Wp2,
                                            const float* __restrict__ corr,
                                            const float* __restrict__ Wb,
                                            f16* __restrict__ Wph,
                                            f16* __restrict__ corrT,
                                            uint16_t* __restrict__ Wbh) {
    const int t = blockIdx.x * 256 + threadIdx.x;
    if (t < 3 * 196608) {
        const int z = t / 196608, i = t % 196608;
        const float* W = (z == 0) ? Wp0 : (z == 1) ? Wp1 : Wp2;
        Wph[(size_t)z * 196608 + i] = (f16)W[i];
    }
    if (t < 65536) {
        const int d = t >> 8, e = t & 255;
        corrT[e * 256 + d] = (f16)corr[d * 256 + e];
        Wbh[t] = (uint16_t)f2bf(Wb[t]);
    }
}

// ---------------------------------------------------------------------------
// MFMA GEMM: C[m,n] = sum_k A[m,k] * B[n,k]  (B [N][K] row-major f16)
// 128x128xBK64 tile, 4 waves, register-prefetch software pipeline.
template <bool A_F16, bool BIAS>
__global__ __launch_bounds__(256) void mfma_gemm(
    const float* __restrict__ A32a, const float* __restrict__ A32b,
    const float* __restrict__ A32c, const f16* __restrict__ A16,
    const f16* __restrict__ Bh, const float* __restrict__ biasA,
    const float* __restrict__ biasB, const float* __restrict__ biasC,
    f16* __restrict__ Ch, int K) {
    const int tid = threadIdx.x;
    const int n0 = blockIdx.x * 128;
    const int m0 = blockIdx.y * 128;
    const int z = blockIdx.z;
    const float* A32 = (z == 0) ? A32a : (z == 1) ? A32b : A32c;
    const float* bias = (z == 0) ? biasA : (z == 1) ? biasB : biasC;
    const f16* Bz = Bh + (size_t)z * 256 * K;
    f16* Cz = Ch + (size_t)z * MROWS * 256;

    __shared__ __align__(16) f16 AhS[8192];  // 16 KB
    __shared__ __align__(16) f16 BhS[8192];  // 16 KB

    const int lane = tid & 63;
    const int w = tid >> 6;
    const int ma = (w >> 1) * 4;
    const int nb = (w & 1) * 4;
    const int srow = tid >> 3;   // 0..31
    const int sc8 = tid & 7;     // 0..7

    f32x4 acc[4][4];
#pragma unroll
    for (int i = 0; i < 4; i++)
#pragma unroll
        for (int j = 0; j < 4; j++) acc[i][j] = (f32x4){0.f, 0.f, 0.f, 0.f};

    float4 aLo[4], aHi[4];
    uint4 aLd[4], bLd[4];
    // prologue: prefetch k0=0
#pragma unroll
    for (int r = 0; r < 4; r++) {
        const int row = srow + 32 * r;
        if constexpr (A_F16) {
            aLd[r] = *(const uint4*)(A16 + (size_t)(m0 + row) * K + sc8 * 8);
        } else {
            const float* p = A32 + (size_t)(m0 + row) * K + sc8 * 8;
            aLo[r] = *(const float4*)p;
            aHi[r] = *(const float4*)(p + 4);
        }
        bLd[r] = *(const uint4*)(Bz + (size_t)(n0 + row) * K + sc8 * 8);
    }

    for (int k0 = 0; k0 < K; k0 += 64) {
        __syncthreads();  // prev compute's frag reads complete
#pragma unroll
        for (int r = 0; r < 4; r++) {
            const int row = srow + 32 * r;
            const int unit = (((sc8 >> 2) * 8 + (row >> 4)) * 64 + (row & 15) + 16 * (sc8 & 3)) ^ (sc8 & 3);
            if constexpr (A_F16) {
                *(uint4*)&AhS[unit * 8] = aLd[r];
            } else {
                f16x8v h;
                h[0] = (f16)aLo[r].x; h[1] = (f16)aLo[r].y; h[2] = (f16)aLo[r].z; h[3] = (f16)aLo[r].w;
                h[4] = (f16)aHi[r].x; h[5] = (f16)aHi[r].y; h[6] = (f16)aHi[r].z; h[7] = (f16)aHi[r].w;
                *(f16x8v*)&AhS[unit * 8] = h;
            }
            *(uint4*)&BhS[unit * 8] = bLd[r];
        }
        __syncthreads();
        if (k0 + 64 < K) {  // prefetch next tile; overlaps with compute below
            const int kn = k0 + 64;
#pragma unroll
            for (int r = 0; r < 4; r++) {
                const int row = srow + 32 * r;
                if constexpr (A_F16) {
                    aLd[r] = *(const uint4*)(A16 + (size_t)(m0 + row) * K + kn + sc8 * 8);
                } else {
                    const float* p = A32 + (size_t)(m0 + row) * K + kn + sc8 * 8;
                    aLo[r] = *(const float4*)p;
                    aHi[r] = *(const float4*)(p + 4);
                }
                bLd[r] = *(const uint4*)(Bz + (size_t)(n0 + row) * K + kn + sc8 * 8);
            }
        }
#pragma unroll
        for (int kh = 0; kh < 2; kh++) {
            f16x8v af[4], bf[4];
#pragma unroll
            for (int i = 0; i < 4; i++)
                af[i] = *(const f16x8v*)&AhS[((((kh * 8 + ma + i) * 64 + lane)) ^ (lane >> 4)) * 8];
#pragma unroll
            for (int j = 0; j < 4; j++)
                bf[j] = *(const f16x8v*)&BhS[((((kh * 8 + nb + j) * 64 + lane)) ^ (lane >> 4)) * 8];
#pragma unroll
            for (int i = 0; i < 4; i++)
#pragma unroll
                for (int j = 0; j < 4; j++)
                    acc[i][j] = __builtin_amdgcn_mfma_f32_16x16x32_f16(af[i], bf[j], acc[i][j], 0, 0, 0);
        }
    }

    // epilogue through LDS for coalesced stores
    f16* Ce = AhS;
    __syncthreads();
    const int cr = lane & 15, qr = lane >> 4;
    const int mwl = (w >> 1) * 64;
    const int nwl = (w & 1) * 64;
#pragma unroll
    for (int i = 0; i < 4; i++) {
#pragma unroll
        for (int j = 0; j < 4; j++) {
            const int col = nwl + j * 16 + cr;
            const float bv = BIAS ? bias[n0 + col] : 0.f;
#pragma unroll
            for (int r = 0; r < 4; r++) {
                const int row = mwl + i * 16 + qr * 4 + r;
                Ce[row * 128 + col] = (f16)(acc[i][j][r] + bv);
            }
        }
    }
    __syncthreads();
#pragma unroll
    for (int r = 0; r < 8; r++) {
        const int f = r * 256 + tid;
        const int row = f >> 4, c16 = f & 15;
        uint4 v = *(const uint4*)&Ce[row * 128 + c16 * 8];
        *(uint4*)(Cz + (size_t)(m0 + row) * 256 + n0 + c16 * 8) = v;
    }
}

// ---------------------------------------------------------------------------
// Fused per-batch attention: for b, for q in {0,1}:
//   cc = ac_b @ other_q^T (MFMA f16, K=256) -> dual softmax -> apply (fp32) -> fused bf16
__global__ __launch_bounds__(256) void fused_attn(const f16* __restrict__ proj0,
                                                  const f16* __restrict__ proj1,
                                                  const f16* __restrict__ proj2,
                                                  const f16* __restrict__ ac,
                                                  uint16_t* __restrict__ fused) {
    const int b = blockIdx.x;
    __shared__ __align__(16) f16 anchorS[64 * 264];  // [i][d] pad264, 33 KB
    __shared__ __align__(16) f16 otherS[64 * 264];   // [j][d] pad264, 33 KB
    __shared__ __align__(16) f16 acS[64 * 264];      // [i][e] pad264, 33 KB
    __shared__ float sc[64][66];                     // logits
    __shared__ __align__(16) float att0[64][68];     // a_att [k=i][m=j]
    __shared__ __align__(16) float att1[64][68];     // o_att^T [k=j][m=i]
    __shared__ float cmax[64], csum[64], rmax[64], rsum[64];

    const int tid = threadIdx.x;
    const int lane = tid & 63;
    const int w = tid >> 6;
    const int tx = tid & 31;   // step-2 d-tile
    const int ty = tid >> 5;   // step-2 token-tile

    // stage anchor + ac (once)
    {
        const f16* a_src = proj0 + (size_t)b * 16384;
        const f16* c_src = ac + (size_t)b * 16384;
#pragma unroll
        for (int r = 0; r < 8; r++) {
            const int f = r * 256 + tid;
            const int row = f >> 5, c8 = f & 31;
            *(uint4*)&anchorS[row * 264 + c8 * 8] = *(const uint4*)(a_src + row * 256 + c8 * 8);
            *(uint4*)&acS[row * 264 + c8 * 8] = *(const uint4*)(c_src + row * 256 + c8 * 8);
        }
    }

    for (int q = 0; q < 2; q++) {
        const f16* o_src = ((q ? proj2 : proj1)) + (size_t)b * 16384;
        __syncthreads();  // prev q's step-2 reads done; anchor/ac stores visible
#pragma unroll
        for (int r = 0; r < 8; r++) {
            const int f = r * 256 + tid;
            const int row = f >> 5, c8 = f & 31;
            *(uint4*)&otherS[row * 264 + c8 * 8] = *(const uint4*)(o_src + row * 256 + c8 * 8);
        }
        __syncthreads();

        // ---- step 1: cc[i,j] via MFMA, wave w owns i-sub w
        f32x4 acc4[4];
#pragma unroll
        for (int j = 0; j < 4; j++) acc4[j] = (f32x4){0.f, 0.f, 0.f, 0.f};
#pragma unroll
        for (int c = 0; c < 4; c++) {
#pragma unroll
            for (int kc = 0; kc < 2; kc++) {
                const int eoff = c * 64 + kc * 32 + (lane >> 4) * 8;
                f16x8v af = *(const f16x8v*)&acS[(w * 16 + (lane & 15)) * 264 + eoff];
#pragma unroll
                for (int js = 0; js < 4; js++) {
                    f16x8v bf = *(const f16x8v*)&otherS[(js * 16 + (lane & 15)) * 264 + eoff];
                    acc4[js] = __builtin_amdgcn_mfma_f32_16x16x32_f16(af, bf, acc4[js], 0, 0, 0);
                }
            }
        }
        // write cc to sc (C-layout: col=lane&15, row=(lane>>4)*4+r)
#pragma unroll
        for (int js = 0; js < 4; js++)
#pragma unroll
            for (int r = 0; r < 4; r++)
                sc[w * 16 + (lane >> 4) * 4 + r][js * 16 + (lane & 15)] = acc4[js][r];
        __syncthreads();

        // ---- softmax stats
        if (tid < 64) {
            const int j = tid;
            float m = -1e30f;
            for (int i = 0; i < 64; i++) m = fmaxf(m, sc[i][j]);
            float s = 0.f;
            for (int i = 0; i < 64; i++) s += __expf(sc[i][j] - m);
            cmax[j] = m;
            csum[j] = s;
        } else if (tid < 128) {
            const int i = tid - 64;
            float m = -1e30f;
            for (int j = 0; j < 64; j++) m = fmaxf(m, sc[i][j]);
            float s = 0.f;
            for (int j = 0; j < 64; j++) s += __expf(sc[i][j] - m);
            rmax[i] = m;
            rsum[i] = s;
        }
        __syncthreads();
        // normalize into att0 [i][j] (col-softmax) and att1 [j][i] (row-softmax, transposed)
        {
            const int j = tid & 63;
            const int i0 = tid >> 6;
            const float cm = cmax[j];
            const float ci = 1.f / csum[j];
            for (int i = i0; i < 64; i += 4) {
                const float v = sc[i][j];
                att0[i][j] = __expf(v - cm) * ci;
                att1[j][i] = __expf(v - rmax[i]) / rsum[i];
            }
        }
        __syncthreads();

        // ---- step 2: apply (fp32 micro-kernel, all operands in LDS)
        for (int part = 0; part < 2; part++) {
            const float(*att)[68] = part ? att1 : att0;
            const f16* Bmat = part ? otherS : anchorS;
            float acc[8][8];
#pragma unroll
            for (int i = 0; i < 8; i++)
#pragma unroll
                for (int j = 0; j < 8; j++) acc[i][j] = 0.f;
            for (int kk = 0; kk < 64; kk++) {
                float4 a0 = *(const float4*)&att[kk][ty * 8];
                float4 a1 = *(const float4*)&att[kk][ty * 8 + 4];
                f16x8v bh = *(const f16x8v*)&Bmat[kk * 264 + tx * 8];
                float a_[8] = {a0.x, a0.y, a0.z, a0.w, a1.x, a1.y, a1.z, a1.w};
                float b_[8];
#pragma unroll
                for (int j = 0; j < 8; j++) b_[j] = (float)bh[j];
#pragma unroll
                for (int i = 0; i < 8; i++)
#pragma unroll
                    for (int j = 0; j < 8; j++) acc[i][j] = fmaf(a_[i], b_[j], acc[i][j]);
            }
            const int c0 = q * 512 + part * 256 + tx * 8;
#pragma unroll
            for (int r = 0; r < 8; r++) {
                const int s = ty * 8 + r;  // output token
                f16x8v rv = *(const f16x8v*)&Bmat[s * 264 + tx * 8];
                uint4 pk;
                pk.x = f2bf(acc[r][0] + (float)rv[0]) | (f2bf(acc[r][1] + (float)rv[1]) << 16);
                pk.y = f2bf(acc[r][2] + (float)rv[2]) | (f2bf(acc[r][3] + (float)rv[3]) << 16);
                pk.z = f2bf(acc[r][4] + (float)rv[4]) | (f2bf(acc[r][5] + (float)rv[5]) << 16);
                pk.w = f2bf(acc[r][6] + (float)rv[6]) | (f2bf(acc[r][7] + (float)rv[7]) << 16);
                *(uint4*)(fused + (size_t)(b * 64 + s) * FIN + c0) = pk;
            }
        }
    }
}

// ---------------------------------------------------------------------------
// final: h = fused(bf16) @ Wbh^T + bb; LayerNorm over 64; ReLU. MFMA bf16.
// 128 rows/block, N=64, K=1024 in BK=64 chunks.
__global__ __launch_bounds__(256) void final_ln(const uint16_t* __restrict__ fused,
                                                const uint16_t* __restrict__ Wbh,
                                                const float* __restrict__ bb,
                                                const float* __restrict__ gamma,
                                                const float* __restrict__ beta,
                                                float* __restrict__ out) {
    const int m0 = blockIdx.x * 128;
    __shared__ __align__(16) uint16_t AS[8192];  // 128x64 bf16, frag-contig swizzled
    __shared__ __align__(16) uint16_t BS[4096];  // 64x64 bf16
    __shared__ float sh[128][66];
    const int tid = threadIdx.x;
    const int lane = tid & 63;
    const int w = tid >> 6;

    f32x4 acc[2][4];
#pragma unroll
    for (int i = 0; i < 2; i++)
#pragma unroll
        for (int j = 0; j < 4; j++) acc[i][j] = (f32x4){0.f, 0.f, 0.f, 0.f};

    for (int k0 = 0; k0 < FIN; k0 += 64) {
        __syncthreads();
#pragma unroll
        for (int r = 0; r < 4; r++) {  // A: 1024 units
            const int f = r * 256 + tid;
            const int row = f >> 3, k8 = f & 7;
            const int unit = ((((k8 >> 2) * 8 + (row >> 4)) * 64 + (row & 15) + 16 * (k8 & 3)) ^ (k8 & 3));
            *(uint4*)&AS[unit * 8] = *(const uint4*)(fused + (size_t)(m0 + row) * FIN + k0 + k8 * 8);
        }
#pragma unroll
        for (int r = 0; r < 2; r++) {  // B: 512 units
            const int f = r * 256 + tid;
            const int row = f >> 3, k8 = f & 7;
            const int unit = ((((k8 >> 2) * 4 + (row >> 4)) * 64 + (row & 15) + 16 * (k8 & 3)) ^ (k8 & 3));
            *(uint4*)&BS[unit * 8] = *(const uint4*)(Wbh + (size_t)row * FIN + k0 + k8 * 8);
        }
        __syncthreads();
#pragma unroll
        for (int kh = 0; kh < 2; kh++) {
            short8 af[2], bf[4];
#pragma unroll
            for (int i = 0; i < 2; i++)
                af[i] = *(const short8*)&AS[((((kh * 8 + w * 2 + i) * 64 + lane)) ^ (lane >> 4)) * 8];
#pragma unroll
            for (int j = 0; j < 4; j++)
                bf[j] = *(const short8*)&BS[((((kh * 4 + j) * 64 + lane)) ^ (lane >> 4)) * 8];
#pragma unroll
            for (int i = 0; i < 2; i++)
#pragma unroll
                for (int j = 0; j < 4; j++)
                    acc[i][j] = __builtin_amdgcn_mfma_f32_16x16x32_bf16(af[i], bf[j], acc[i][j], 0, 0, 0);
        }
    }
    __syncthreads();
    // epilogue: wave w rows w*32..+31
    const int cr = lane & 15, qr = lane >> 4;
#pragma unroll
    for (int i = 0; i < 2; i++) {
#pragma unroll
        for (int j = 0; j < 4; j++) {
            const int col = j * 16 + cr;
            const float bv = bb[col];
#pragma unroll
            for (int r = 0; r < 4; r++)
                sh[w * 32 + i * 16 + qr * 4 + r][col] = acc[i][j][r] + bv;
        }
    }
    __syncthreads();
    // LayerNorm: thread pair (2 per row)
    const int row = tid >> 1;
    const int half = tid & 1;
    float s = 0.f, ss = 0.f;
#pragma unroll
    for (int c = 0; c < 32; c++) {
        const float v = sh[row][half * 32 + c];
        s += v;
        ss += v * v;
    }
    s += __shfl_xor(s, 1);
    ss += __shfl_xor(ss, 1);
    const float mu = s * (1.f / 64.f);
    const float inv = rsqrtf(ss * (1.f / 64.f) - mu * mu + 1e-5f);
#pragma unroll
    for (int c4 = 0; c4 < 8; c4++) {
        const int col = half * 32 + c4 * 4;
        float4 g = *(const float4*)(gamma + col);
        float4 be = *(const float4*)(beta + col);
        float4 v;
        v.x = fmaxf((sh[row][col + 0] - mu) * inv * g.x + be.x, 0.f);
        v.y = fmaxf((sh[row][col + 1] - mu) * inv * g.y + be.y, 0.f);
        v.z = fmaxf((sh[row][col + 2] - mu) * inv * g.z + be.z, 0.f);
        v.w = fmaxf((sh[row][col + 3] - mu) * inv * g.w + be.w, 0.f);
        *(float4*)(out + (size_t)(m0 + row) * 64 + col) = v;
    }
}

extern "C" void kernel_launch(void* const* d_in, const int* in_sizes, int n_in,
                              void* d_out, int out_size, void* d_ws, size_t ws_size,
                              hipStream_t stream) {
    const float* latent0 = (const float*)d_in[0];
    const float* Wp0 = (const float*)d_in[1];
    const float* bp0 = (const float*)d_in[2];
    const float* latent1 = (const float*)d_in[3];
    const float* Wp1 = (const float*)d_in[4];
    const float* bp1 = (const float*)d_in[5];
    const float* latent2 = (const float*)d_in[6];
    const float* Wp2 = (const float*)d_in[7];
    const float* bp2 = (const float*)d_in[8];
    const float* corr = (const float*)d_in[9];
    const float* Wb = (const float*)d_in[10];
    const float* bb = (const float*)d_in[11];
    const float* gamma = (const float*)d_in[12];
    const float* beta = (const float*)d_in[13];

    char* ws = (char*)d_ws;
    f16* proj_h = (f16*)ws;                                   // 48 MB
    f16* ac_h = (f16*)(ws + 48ull * 1024 * 1024);             // 16 MB
    uint16_t* fused = (uint16_t*)(ws + 64ull * 1024 * 1024);  // 64 MB
    f16* Wph = (f16*)(ws + 128ull * 1024 * 1024);             // 1.125 MB
    f16* corrT = (f16*)(ws + 130ull * 1024 * 1024);           // 128 KB
    uint16_t* Wbh = (uint16_t*)(ws + 131ull * 1024 * 1024);   // 128 KB

    float* out = (float*)d_out;
    dim3 blk(256);

    prep<<<2304, blk, 0, stream>>>(Wp0, Wp1, Wp2, corr, Wb, Wph, corrT, Wbh);

    // projections (fp16 MFMA, pipelined)
    mfma_gemm<false, true><<<dim3(2, 256, 3), blk, 0, stream>>>(
        latent0, latent1, latent2, (const f16*)nullptr, Wph, bp0, bp1, bp2, proj_h, Esz);

    // ac = proj0 @ corr
    mfma_gemm<true, false><<<dim3(2, 256, 1), blk, 0, stream>>>(
        (const float*)nullptr, (const float*)nullptr, (const float*)nullptr, proj_h,
        corrT, (const float*)nullptr, (const float*)nullptr, (const float*)nullptr,
        ac_h, Dsz);

    const f16* proj1_h = proj_h + (size_t)MROWS * 256;
    const f16* proj2_h = proj_h + 2ull * MROWS * 256;

    // fused cc + softmax + apply
    fused_attn<<<Bsz, blk, 0, stream>>>(proj_h, proj1_h, proj2_h, ac_h, fused);

    // bottleneck GEMM + LayerNorm + ReLU (bf16 MFMA)
    final_ln<<<MROWS / 128, blk, 0, stream>>>(fused, Wbh, bb, gamma, beta, out);

    (void)in_sizes; (void)n_in; (void)out_size; (void)ws_size;
}